// Round 3
// baseline (1282.953 us; speedup 1.0000x reference)
//
#include <hip/hip_runtime.h>
#include <hip/hip_bf16.h>
#include <hip/hip_fp16.h>
#include <stdint.h>

#define BB 2048
#define LL 2048
#define CV 128
#define DD 1024
#define NC 1000
#define EE 6
#define HH 2048

typedef __bf16 bf16_t;
typedef _Float16 f16_t;
typedef __attribute__((ext_vector_type(8))) __bf16 bf16x8;
typedef __attribute__((ext_vector_type(8))) _Float16 f16x8;
typedef __attribute__((ext_vector_type(4))) float f32x4;

__device__ __forceinline__ void gload_lds16(const void* g, void* l)
{
    __builtin_amdgcn_global_load_lds(
        (const __attribute__((address_space(1))) unsigned int*)g,
        (__attribute__((address_space(3))) unsigned int*)l, 16, 0, 0);
}

// ---- prep: split conv2_w into bf16 hi/lo, pre-swizzled slices --------------
// slice t = cb*5 + kk (16KB = 8192 shorts): [split(hi,lo)][co 128][ci 32]
// within-plane short index: (co*32 + j) ^ ((co&7)<<3)
__global__ void k_prep_w2(const float* __restrict__ w2, bf16_t* __restrict__ wsw)
{
    int idx = blockIdx.x * 256 + threadIdx.x;
    if (idx >= 5 * 128 * 128) return;
    int kk = idx % 5;
    int t2 = idx / 5;
    int ci = t2 & 127;
    int co = t2 >> 7;
    float v = w2[idx];
    bf16_t h = (bf16_t)v;
    bf16_t l = (bf16_t)(v - (float)h);
    int cb = ci >> 5, j = ci & 31;
    int t  = cb * 5 + kk;
    int si = (co * 32 + j) ^ ((co & 7) << 3);
    wsw[(size_t)t * 8192 + si]        = h;
    wsw[(size_t)t * 8192 + 4096 + si] = l;
}

// ---- fused conv1(fp32,reg-w1) + conv2(bf16x3 MFMA, LDS-pipelined) + mean ---
__launch_bounds__(256, 3)
__global__ void k_conv(const float* __restrict__ x,  const float* __restrict__ w1,
                       const float* __restrict__ b1, const bf16_t* __restrict__ wsw,
                       const float* __restrict__ b2, float* __restrict__ hbar)
{
    __shared__ __align__(16) float w1s[640];
    __shared__ __align__(16) float b1s[128];
    __shared__ __align__(16) float b2s[128];
    __shared__ __align__(16) short h1s[2][136 * 32];   // [hi/lo][r 136][ci 32] swizzled
    __shared__ __align__(16) short wlds[2][2][4096];   // [buf][hi/lo][co128*ci32] swizzled

    const int tid  = threadIdx.x;
    const int b    = blockIdx.x;
    const int lane = tid & 63;
    const int wid  = tid >> 6;
    const int l15  = lane & 15, lg = lane >> 4;
    const int wm   = wid >> 1,  wn = wid & 1;      // co-half / t2-half
    const int jo   = tid & 3;                      // ci-octet in conv1
    const int rg   = tid >> 2;                     // row group in conv1

    for (int i = tid; i < 640; i += 256) w1s[i] = w1[i];
    if (tid < 128) { b1s[tid] = b1[tid]; b2s[tid] = b2[tid]; }

    // stage W slice 0 into wlds[0]
    {
        const bf16_t* src = wsw + (size_t)(wid * 4) * 512 + lane * 8;
        short* dst = ((short*)wlds) + (wid * 4) * 512;
#pragma unroll
        for (int o = 0; o < 4; ++o)
            gload_lds16(src + o * 512, dst + o * 512);
    }
    __syncthreads();

    const float* xrow = x + (size_t)b * LL;

    float racc[4][4];
#pragma unroll
    for (int m = 0; m < 4; ++m)
#pragma unroll
        for (int r = 0; r < 4; ++r) racc[m][r] = 0.f;

    for (int c = 0; c < 8; ++c) {
        const int t1base = 128 * c - 2;

        f32x4 acc[4][2];
#pragma unroll
        for (int m = 0; m < 4; ++m)
#pragma unroll
            for (int n = 0; n < 2; ++n)
#pragma unroll
                for (int r = 0; r < 4; ++r) acc[m][n][r] = 0.f;

        for (int cb = 0; cb < 4; ++cb) {
            // ---- conv1 for this cb's 32-ci slice: 8 ci per thread, b128 writes
            const int ci0 = cb * 32 + jo * 8;
            float wf[40], br8[8];
#pragma unroll
            for (int q = 0; q < 10; ++q)
                *reinterpret_cast<float4*>(&wf[q * 4]) =
                    *reinterpret_cast<const float4*>(&w1s[ci0 * 5 + q * 4]);
            *reinterpret_cast<float4*>(&br8[0]) = *reinterpret_cast<const float4*>(&b1s[ci0]);
            *reinterpret_cast<float4*>(&br8[4]) = *reinterpret_cast<const float4*>(&b1s[ci0 + 4]);

#pragma unroll
            for (int it = 0; it < 3; ++it) {
                int r = rg + it * 64;
                if (r < 136) {
                    int t1 = t1base + r;
                    bool valid = (unsigned)t1 < 1024u;
                    float xv[5];
#pragma unroll
                    for (int kk = 0; kk < 5; ++kk) {
                        int xg = 2 * t1 - 2 + kk;
                        xv[kk] = (valid && (unsigned)xg < 2048u) ? xrow[xg] : 0.f;
                    }
                    bf16x8 hv, lv;
#pragma unroll
                    for (int u = 0; u < 8; ++u) {
                        float v = 0.f;
                        if (valid) {
                            v = br8[u];
#pragma unroll
                            for (int kk = 0; kk < 5; ++kk) v += wf[u * 5 + kk] * xv[kk];
                            v = fmaxf(v, 0.f);
                        }
                        bf16_t h = (bf16_t)v;
                        hv[u] = h;
                        lv[u] = (bf16_t)(v - (float)h);
                    }
                    int si = (r * 32 + jo * 8) ^ (((r >> 1) & 7) << 3);
                    *reinterpret_cast<bf16x8*>(&h1s[0][si]) = hv;
                    *reinterpret_cast<bf16x8*>(&h1s[1][si]) = lv;
                }
            }
            __syncthreads();

            // ---- 5 K-steps (K=32 each), W slice double-buffered w/ prefetch
            for (int k = 0; k < 5; ++k) {
                const int t  = cb * 5 + k;
                const int tn = (t + 1) % 20;
                {
                    const bf16_t* src = wsw + (size_t)tn * 8192 + (wid * 4) * 512 + lane * 8;
                    short* dst = ((short*)wlds) + (tn & 1) * 8192 + (wid * 4) * 512;
#pragma unroll
                    for (int o = 0; o < 4; ++o)
                        gload_lds16(src + o * 512, dst + o * 512);
                }
                const short* wp = ((short*)wlds) + (t & 1) * 8192;
                bf16x8 ah[4], al[4];
#pragma unroll
                for (int m = 0; m < 4; ++m) {
                    int co_l = wm * 64 + m * 16 + l15;
                    int si = (co_l * 32 + lg * 8) ^ ((l15 & 7) << 3);
                    ah[m] = *reinterpret_cast<const bf16x8*>(wp + si);
                    al[m] = *reinterpret_cast<const bf16x8*>(wp + 4096 + si);
                }
                bf16x8 bh[2], bl[2];
#pragma unroll
                for (int n = 0; n < 2; ++n) {
                    int r = 2 * (wn * 32 + n * 16 + l15) + k;
                    int si = (r * 32 + lg * 8) ^ (((r >> 1) & 7) << 3);
                    bh[n] = *reinterpret_cast<const bf16x8*>(&h1s[0][si]);
                    bl[n] = *reinterpret_cast<const bf16x8*>(&h1s[1][si]);
                }
#pragma unroll
                for (int m = 0; m < 4; ++m)
#pragma unroll
                    for (int n = 0; n < 2; ++n) {
                        acc[m][n] = __builtin_amdgcn_mfma_f32_16x16x32_bf16(ah[m], bh[n], acc[m][n], 0, 0, 0);
                        acc[m][n] = __builtin_amdgcn_mfma_f32_16x16x32_bf16(ah[m], bl[n], acc[m][n], 0, 0, 0);
                        acc[m][n] = __builtin_amdgcn_mfma_f32_16x16x32_bf16(al[m], bh[n], acc[m][n], 0, 0, 0);
                    }
                __syncthreads();
            }
        }
        // chunk epilogue: relu(z+b2) and accumulate t2 partial sums
#pragma unroll
        for (int m = 0; m < 4; ++m)
#pragma unroll
            for (int r = 0; r < 4; ++r) {
                int co = wm * 64 + m * 16 + lg * 4 + r;
                float bias = b2s[co];
                racc[m][r] += fmaxf(acc[m][0][r] + bias, 0.f) + fmaxf(acc[m][1][r] + bias, 0.f);
            }
    }

    // reduce 16 t2-columns held across l15 lanes
#pragma unroll
    for (int m = 0; m < 4; ++m)
#pragma unroll
        for (int r = 0; r < 4; ++r) {
            float v = racc[m][r];
            v += __shfl_xor(v, 1);
            v += __shfl_xor(v, 2);
            v += __shfl_xor(v, 4);
            v += __shfl_xor(v, 8);
            racc[m][r] = v;
        }
    float* red = (float*)wlds;   // wlds dead now (vmcnt drained by last barrier)
    if (l15 == 0) {
#pragma unroll
        for (int m = 0; m < 4; ++m)
#pragma unroll
            for (int r = 0; r < 4; ++r)
                red[wid * 64 + m * 16 + lg * 4 + r] = racc[m][r];
    }
    __syncthreads();
    if (tid < 128) {
        int wm2 = tid >> 6, loc = tid & 63;
        float s = red[(wm2 * 2 + 0) * 64 + loc] + red[(wm2 * 2 + 1) * 64 + loc];
        hbar[(size_t)b * 128 + tid] = s * (1.f / 512.f);
    }
}

// ---------------- proj: h = hbar @ proj_w^T + proj_b (pure fp32) -------------
__launch_bounds__(256)
__global__ void k_proj(const float* __restrict__ hbar, const float* __restrict__ pw,
                       const float* __restrict__ pb, float* __restrict__ h)
{
    __shared__ float hbs[64 * 128];
    const int tid = threadIdx.x;
    const int b0 = blockIdx.x * 64, d0 = blockIdx.y * 64;
    for (int i = tid * 4; i < 64 * 128; i += 1024)
        *reinterpret_cast<float4*>(&hbs[i]) =
            *reinterpret_cast<const float4*>(&hbar[(size_t)b0 * 128 + i]);
    __syncthreads();
    const int tx = tid & 15, ty = tid >> 4;
    float acc[4][4];
#pragma unroll
    for (int i = 0; i < 4; ++i)
#pragma unroll
        for (int j = 0; j < 4; ++j) acc[i][j] = 0.f;
    const float* pwr[4];
#pragma unroll
    for (int j = 0; j < 4; ++j) pwr[j] = pw + (size_t)(d0 + tx * 4 + j) * 128;
    for (int k = 0; k < 128; k += 4) {
        float4 wv[4], av[4];
#pragma unroll
        for (int j = 0; j < 4; ++j) wv[j] = *reinterpret_cast<const float4*>(pwr[j] + k);
#pragma unroll
        for (int i = 0; i < 4; ++i) av[i] = *reinterpret_cast<const float4*>(&hbs[(ty * 4 + i) * 128 + k]);
#pragma unroll
        for (int i = 0; i < 4; ++i)
#pragma unroll
            for (int j = 0; j < 4; ++j)
                acc[i][j] += av[i].x * wv[j].x + av[i].y * wv[j].y +
                             av[i].z * wv[j].z + av[i].w * wv[j].w;
    }
#pragma unroll
    for (int i = 0; i < 4; ++i) {
        int bb = b0 + ty * 4 + i;
#pragma unroll
        for (int j = 0; j < 4; ++j) {
            int d = d0 + tx * 4 + j;
            h[(size_t)bb * DD + d] = acc[i][j] + pb[d];
        }
    }
}

// ---------------- router: logits, softmax, top-2 -> combine[b][8] ------------
__launch_bounds__(256)
__global__ void k_router(const float* __restrict__ h, const float* __restrict__ rw,
                         const float* __restrict__ rb, float* __restrict__ comb)
{
    const int lane = threadIdx.x & 63;
    const int b = blockIdx.x * 4 + (threadIdx.x >> 6);
    float part[6] = {0.f, 0.f, 0.f, 0.f, 0.f, 0.f};
    for (int j = 0; j < 16; ++j) {
        int d = j * 64 + lane;
        float hv = h[(size_t)b * DD + d];
#pragma unroll
        for (int e = 0; e < 6; ++e) part[e] += rw[e * DD + d] * hv;
    }
#pragma unroll
    for (int e = 0; e < 6; ++e) {
        float v = part[e];
        for (int off = 32; off > 0; off >>= 1) v += __shfl_xor(v, off);
        part[e] = v;
    }
    if (lane == 0) {
        float lgt[6];
#pragma unroll
        for (int e = 0; e < 6; ++e) lgt[e] = part[e] + rb[e];
        int i1 = 0;
#pragma unroll
        for (int e = 1; e < 6; ++e) if (lgt[e] > lgt[i1]) i1 = e;
        int i2 = -1;
#pragma unroll
        for (int e = 0; e < 6; ++e)
            if (e != i1 && (i2 < 0 || lgt[e] > lgt[i2])) i2 = e;
        float mx = lgt[i1], s = 0.f, ex[6];
#pragma unroll
        for (int e = 0; e < 6; ++e) { ex[e] = expf(lgt[e] - mx); s += ex[e]; }
        float inv = 1.f / s;
#pragma unroll
        for (int e = 0; e < 6; ++e) comb[b * 8 + e] = 0.f;
        comb[b * 8 + 6] = 0.f; comb[b * 8 + 7] = 0.f;
        comb[b * 8 + i1] = ex[i1] * inv;
        comb[b * 8 + i2] = ex[i2] * inv;
    }
}

// ---------------- generic fp16 MFMA GEMM: C = A @ B^T ------------------------
__device__ inline f16x8 cvt8(const float4 a, const float4 b)
{
    f16x8 r;
    r[0] = (f16_t)a.x; r[1] = (f16_t)a.y; r[2] = (f16_t)a.z; r[3] = (f16_t)a.w;
    r[4] = (f16_t)b.x; r[5] = (f16_t)b.y; r[6] = (f16_t)b.z; r[7] = (f16_t)b.w;
    return r;
}

template<bool F16SRC, int ROWS>
__device__ inline void stage_tile(const void* __restrict__ src, f16_t* __restrict__ dst,
                                  int rowG0, int K, int k0, int maxRow, int tid)
{
    constexpr int PERTHR = ROWS * 64 / 256;
    constexpr int TPR = 64 / PERTHR;
    const int row  = tid / TPR;
    const int col0 = (tid % TPR) * PERTHR;
    const bool ok = (rowG0 + row) < maxRow;
    f16_t* d = dst + row * 72 + col0;
    if constexpr (F16SRC) {
        const uint4* s = reinterpret_cast<const uint4*>(
            (const f16_t*)src + (size_t)(rowG0 + row) * K + k0 + col0);
#pragma unroll
        for (int j = 0; j < PERTHR / 8; ++j) {
            uint4 v = ok ? s[j] : make_uint4(0, 0, 0, 0);
            reinterpret_cast<uint4*>(d)[j] = v;
        }
    } else {
        const float4* s = reinterpret_cast<const float4*>(
            (const float*)src + (size_t)(rowG0 + row) * K + k0 + col0);
#pragma unroll
        for (int j = 0; j < PERTHR / 8; ++j) {
            float4 a = ok ? s[2 * j]     : make_float4(0.f, 0.f, 0.f, 0.f);
            float4 c = ok ? s[2 * j + 1] : make_float4(0.f, 0.f, 0.f, 0.f);
            reinterpret_cast<f16x8*>(d)[j] = cvt8(a, c);
        }
    }
}

// EPI: 1 = hid (relu->f16 out), 2 = eo (scale by combine, accumulate moe), 3 = cls
template<int EPI, bool AF16, int NFRAG>
__launch_bounds__(256, 2)
__global__ void k_gemm(const void* __restrict__ Ap, const float* __restrict__ Bp,
                       const float* __restrict__ bias, float* __restrict__ outF,
                       f16_t* __restrict__ outH, const float* __restrict__ combine,
                       float* __restrict__ moe, int M, int N, int K, int maxNRow, int e)
{
    constexpr int BN = NFRAG * 32;
    __shared__ f16_t As[128 * 72];
    __shared__ f16_t Bs[BN * 72];
    const int tid = threadIdx.x;
    const int m0 = blockIdx.x * 128, n0 = blockIdx.y * BN;
    const int lane = tid & 63, wid = tid >> 6;
    const int l15 = lane & 15, lg = lane >> 4;
    const int wm = wid >> 1, wn = wid & 1;

    f32x4 acc[4][NFRAG];
#pragma unroll
    for (int i = 0; i < 4; ++i)
#pragma unroll
        for (int j = 0; j < NFRAG; ++j)
#pragma unroll
            for (int r = 0; r < 4; ++r) acc[i][j][r] = 0.f;

    for (int k0 = 0; k0 < K; k0 += 64) {
        __syncthreads();
        stage_tile<AF16, 128>(Ap, As, m0, K, k0, M, tid);
        stage_tile<false, BN>((const void*)Bp, Bs, n0, K, k0, maxNRow, tid);
        __syncthreads();
#pragma unroll
        for (int kk = 0; kk < 64; kk += 32) {
            f16x8 af[4], bq[NFRAG];
#pragma unroll
            for (int i = 0; i < 4; ++i)
                af[i] = *reinterpret_cast<const f16x8*>(As + (wm * 64 + i * 16 + l15) * 72 + kk + lg * 8);
#pragma unroll
            for (int j = 0; j < NFRAG; ++j)
                bq[j] = *reinterpret_cast<const f16x8*>(Bs + (wn * (BN / 2) + j * 16 + l15) * 72 + kk + lg * 8);
#pragma unroll
            for (int i = 0; i < 4; ++i)
#pragma unroll
                for (int j = 0; j < NFRAG; ++j)
                    acc[i][j] = __builtin_amdgcn_mfma_f32_16x16x32_f16(af[i], bq[j], acc[i][j], 0, 0, 0);
        }
    }
#pragma unroll
    for (int i = 0; i < 4; ++i) {
#pragma unroll
        for (int j = 0; j < NFRAG; ++j) {
#pragma unroll
            for (int r = 0; r < 4; ++r) {
                int row = m0 + wm * 64 + i * 16 + lg * 4 + r;
                int col = n0 + wn * (BN / 2) + j * 16 + l15;
                float c = acc[i][j][r];
                if (EPI == 1) {
                    float v = fmaxf(c + bias[col], 0.f);
                    outH[(size_t)row * N + col] = (f16_t)v;
                } else if (EPI == 2) {
                    float v = c + bias[col];
                    float w = combine[row * 8 + e];
                    float prev = (e == 0) ? 0.f : moe[(size_t)row * N + col];
                    moe[(size_t)row * N + col] = prev + w * v;
                } else {
                    if (col < maxNRow)
                        outF[(size_t)row * maxNRow + col] = c + bias[col];
                }
            }
        }
    }
}

// -----------------------------------------------------------------------------
extern "C" void kernel_launch(void* const* d_in, const int* in_sizes, int n_in,
                              void* d_out, int out_size, void* d_ws, size_t ws_size,
                              hipStream_t stream)
{
    const float* x   = (const float*)d_in[0];
    const float* w1  = (const float*)d_in[1];
    const float* b1  = (const float*)d_in[2];
    const float* w2  = (const float*)d_in[3];
    const float* b2  = (const float*)d_in[4];
    const float* pw  = (const float*)d_in[5];
    const float* pb  = (const float*)d_in[6];
    const float* rw  = (const float*)d_in[7];
    const float* rb  = (const float*)d_in[8];
    const float* ew1 = (const float*)d_in[9];
    const float* eb1 = (const float*)d_in[10];
    const float* ew2 = (const float*)d_in[11];
    const float* eb2 = (const float*)d_in[12];
    const float* cw  = (const float*)d_in[13];
    const float* cb  = (const float*)d_in[14];
    float* out = (float*)d_out;

    char* ws = (char*)d_ws;
    bf16_t* wsw  = (bf16_t*)(ws + 0);          //   320 KB (20 slices x 16KB)
    float*  hbar = (float*)(ws + 327680);      //     1 MB
    float*  h    = (float*)(ws + 1376256);     //     8 MB
    float*  comb = (float*)(ws + 9764864);     //    64 KB
    f16_t*  hid  = (f16_t*)(ws + 9830400);     //     8 MB
    float*  moe  = (float*)(ws + 18219008);    //     8 MB

    k_prep_w2<<<320, 256, 0, stream>>>(w2, wsw);
    k_conv<<<2048, 256, 0, stream>>>(x, w1, b1, wsw, b2, hbar);
    k_proj<<<dim3(32, 16), 256, 0, stream>>>(hbar, pw, pb, h);
    k_router<<<512, 256, 0, stream>>>(h, rw, rb, comb);
    for (int e = 0; e < 6; ++e) {
        k_gemm<1, false, 4><<<dim3(16, 16), 256, 0, stream>>>(
            (const void*)h, ew1 + (size_t)e * HH * DD, eb1 + (size_t)e * HH,
            nullptr, hid, nullptr, nullptr, BB, HH, DD, 1 << 30, e);
        k_gemm<2, true, 2><<<dim3(16, 16), 256, 0, stream>>>(
            (const void*)hid, ew2 + (size_t)e * DD * HH, eb2 + (size_t)e * DD,
            nullptr, nullptr, comb, moe, BB, DD, HH, 1 << 30, e);
    }
    k_gemm<3, false, 4><<<dim3(16, 8), 256, 0, stream>>>(
        (const void*)moe, cw, cb, out, nullptr, nullptr, nullptr,
        BB, DD, DD, NC, 0);
}

// Round 4
// 919.990 us; speedup vs baseline: 1.3945x; 1.3945x over previous
//
#include <hip/hip_runtime.h>
#include <hip/hip_bf16.h>
#include <hip/hip_fp16.h>
#include <stdint.h>

#define BB 2048
#define LL 2048
#define CV 128
#define DD 1024
#define NC 1000
#define EE 6
#define HH 2048

typedef __bf16 bf16_t;
typedef _Float16 f16_t;
typedef __attribute__((ext_vector_type(8))) __bf16 bf16x8;
typedef __attribute__((ext_vector_type(8))) _Float16 f16x8;
typedef __attribute__((ext_vector_type(4))) float f32x4;

__device__ __forceinline__ void gload_lds16(const void* g, void* l)
{
    __builtin_amdgcn_global_load_lds(
        (const __attribute__((address_space(1))) unsigned int*)g,
        (__attribute__((address_space(3))) unsigned int*)l, 16, 0, 0);
}

// ---- prep: split conv2_w into bf16 hi/lo, pre-swizzled slices --------------
__global__ void k_prep_w2(const float* __restrict__ w2, bf16_t* __restrict__ wsw)
{
    int idx = blockIdx.x * 256 + threadIdx.x;
    if (idx >= 5 * 128 * 128) return;
    int kk = idx % 5;
    int t2 = idx / 5;
    int ci = t2 & 127;
    int co = t2 >> 7;
    float v = w2[idx];
    bf16_t h = (bf16_t)v;
    bf16_t l = (bf16_t)(v - (float)h);
    int cb = ci >> 5, j = ci & 31;
    int t  = cb * 5 + kk;
    int si = (co * 32 + j) ^ ((co & 7) << 3);
    wsw[(size_t)t * 8192 + si]        = h;
    wsw[(size_t)t * 8192 + 4096 + si] = l;
}

// ---- fused conv1(fp32,reg-w1) + conv2(bf16x3 MFMA, LDS-pipelined) + mean ---
__launch_bounds__(256, 3)
__global__ void k_conv(const float* __restrict__ x,  const float* __restrict__ w1,
                       const float* __restrict__ b1, const bf16_t* __restrict__ wsw,
                       const float* __restrict__ b2, float* __restrict__ hbar)
{
    __shared__ __align__(16) float w1s[640];
    __shared__ __align__(16) float b1s[128];
    __shared__ __align__(16) float b2s[128];
    __shared__ __align__(16) short h1s[2][136 * 32];
    __shared__ __align__(16) short wlds[2][2][4096];

    const int tid  = threadIdx.x;
    const int b    = blockIdx.x;
    const int lane = tid & 63;
    const int wid  = tid >> 6;
    const int l15  = lane & 15, lg = lane >> 4;
    const int wm   = wid >> 1,  wn = wid & 1;
    const int jo   = tid & 3;
    const int rg   = tid >> 2;

    for (int i = tid; i < 640; i += 256) w1s[i] = w1[i];
    if (tid < 128) { b1s[tid] = b1[tid]; b2s[tid] = b2[tid]; }

    {
        const bf16_t* src = wsw + (size_t)(wid * 4) * 512 + lane * 8;
        short* dst = ((short*)wlds) + (wid * 4) * 512;
#pragma unroll
        for (int o = 0; o < 4; ++o)
            gload_lds16(src + o * 512, dst + o * 512);
    }
    __syncthreads();

    const float* xrow = x + (size_t)b * LL;

    float racc[4][4];
#pragma unroll
    for (int m = 0; m < 4; ++m)
#pragma unroll
        for (int r = 0; r < 4; ++r) racc[m][r] = 0.f;

    for (int c = 0; c < 8; ++c) {
        const int t1base = 128 * c - 2;

        f32x4 acc[4][2];
#pragma unroll
        for (int m = 0; m < 4; ++m)
#pragma unroll
            for (int n = 0; n < 2; ++n)
#pragma unroll
                for (int r = 0; r < 4; ++r) acc[m][n][r] = 0.f;

        for (int cb = 0; cb < 4; ++cb) {
            const int ci0 = cb * 32 + jo * 8;
            float wf[40], br8[8];
#pragma unroll
            for (int q = 0; q < 10; ++q)
                *reinterpret_cast<float4*>(&wf[q * 4]) =
                    *reinterpret_cast<const float4*>(&w1s[ci0 * 5 + q * 4]);
            *reinterpret_cast<float4*>(&br8[0]) = *reinterpret_cast<const float4*>(&b1s[ci0]);
            *reinterpret_cast<float4*>(&br8[4]) = *reinterpret_cast<const float4*>(&b1s[ci0 + 4]);

#pragma unroll
            for (int it = 0; it < 3; ++it) {
                int r = rg + it * 64;
                if (r < 136) {
                    int t1 = t1base + r;
                    bool valid = (unsigned)t1 < 1024u;
                    float xv[5];
#pragma unroll
                    for (int kk = 0; kk < 5; ++kk) {
                        int xg = 2 * t1 - 2 + kk;
                        xv[kk] = (valid && (unsigned)xg < 2048u) ? xrow[xg] : 0.f;
                    }
                    bf16x8 hv, lv;
#pragma unroll
                    for (int u = 0; u < 8; ++u) {
                        float v = 0.f;
                        if (valid) {
                            v = br8[u];
#pragma unroll
                            for (int kk = 0; kk < 5; ++kk) v += wf[u * 5 + kk] * xv[kk];
                            v = fmaxf(v, 0.f);
                        }
                        bf16_t h = (bf16_t)v;
                        hv[u] = h;
                        lv[u] = (bf16_t)(v - (float)h);
                    }
                    int si = (r * 32 + jo * 8) ^ (((r >> 1) & 7) << 3);
                    *reinterpret_cast<bf16x8*>(&h1s[0][si]) = hv;
                    *reinterpret_cast<bf16x8*>(&h1s[1][si]) = lv;
                }
            }
            __syncthreads();

            for (int k = 0; k < 5; ++k) {
                const int t  = cb * 5 + k;
                const int tn = (t + 1) % 20;
                {
                    const bf16_t* src = wsw + (size_t)tn * 8192 + (wid * 4) * 512 + lane * 8;
                    short* dst = ((short*)wlds) + (tn & 1) * 8192 + (wid * 4) * 512;
#pragma unroll
                    for (int o = 0; o < 4; ++o)
                        gload_lds16(src + o * 512, dst + o * 512);
                }
                const short* wp = ((short*)wlds) + (t & 1) * 8192;
                bf16x8 ah[4], al[4];
#pragma unroll
                for (int m = 0; m < 4; ++m) {
                    int co_l = wm * 64 + m * 16 + l15;
                    int si = (co_l * 32 + lg * 8) ^ ((l15 & 7) << 3);
                    ah[m] = *reinterpret_cast<const bf16x8*>(wp + si);
                    al[m] = *reinterpret_cast<const bf16x8*>(wp + 4096 + si);
                }
                bf16x8 bh[2], bl[2];
#pragma unroll
                for (int n = 0; n < 2; ++n) {
                    int r = 2 * (wn * 32 + n * 16 + l15) + k;
                    int si = (r * 32 + lg * 8) ^ (((r >> 1) & 7) << 3);
                    bh[n] = *reinterpret_cast<const bf16x8*>(&h1s[0][si]);
                    bl[n] = *reinterpret_cast<const bf16x8*>(&h1s[1][si]);
                }
#pragma unroll
                for (int m = 0; m < 4; ++m)
#pragma unroll
                    for (int n = 0; n < 2; ++n) {
                        acc[m][n] = __builtin_amdgcn_mfma_f32_16x16x32_bf16(ah[m], bh[n], acc[m][n], 0, 0, 0);
                        acc[m][n] = __builtin_amdgcn_mfma_f32_16x16x32_bf16(ah[m], bl[n], acc[m][n], 0, 0, 0);
                        acc[m][n] = __builtin_amdgcn_mfma_f32_16x16x32_bf16(al[m], bh[n], acc[m][n], 0, 0, 0);
                    }
                __syncthreads();
            }
        }
#pragma unroll
        for (int m = 0; m < 4; ++m)
#pragma unroll
            for (int r = 0; r < 4; ++r) {
                int co = wm * 64 + m * 16 + lg * 4 + r;
                float bias = b2s[co];
                racc[m][r] += fmaxf(acc[m][0][r] + bias, 0.f) + fmaxf(acc[m][1][r] + bias, 0.f);
            }
    }

#pragma unroll
    for (int m = 0; m < 4; ++m)
#pragma unroll
        for (int r = 0; r < 4; ++r) {
            float v = racc[m][r];
            v += __shfl_xor(v, 1);
            v += __shfl_xor(v, 2);
            v += __shfl_xor(v, 4);
            v += __shfl_xor(v, 8);
            racc[m][r] = v;
        }
    float* red = (float*)wlds;
    if (l15 == 0) {
#pragma unroll
        for (int m = 0; m < 4; ++m)
#pragma unroll
            for (int r = 0; r < 4; ++r)
                red[wid * 64 + m * 16 + lg * 4 + r] = racc[m][r];
    }
    __syncthreads();
    if (tid < 128) {
        int wm2 = tid >> 6, loc = tid & 63;
        float s = red[(wm2 * 2 + 0) * 64 + loc] + red[(wm2 * 2 + 1) * 64 + loc];
        hbar[(size_t)b * 128 + tid] = s * (1.f / 512.f);
    }
}

// ---------------- proj: h = hbar @ proj_w^T + proj_b (pure fp32) -------------
__launch_bounds__(256)
__global__ void k_proj(const float* __restrict__ hbar, const float* __restrict__ pw,
                       const float* __restrict__ pb, float* __restrict__ h)
{
    __shared__ float hbs[64 * 128];
    const int tid = threadIdx.x;
    const int b0 = blockIdx.x * 64, d0 = blockIdx.y * 64;
    for (int i = tid * 4; i < 64 * 128; i += 1024)
        *reinterpret_cast<float4*>(&hbs[i]) =
            *reinterpret_cast<const float4*>(&hbar[(size_t)b0 * 128 + i]);
    __syncthreads();
    const int tx = tid & 15, ty = tid >> 4;
    float acc[4][4];
#pragma unroll
    for (int i = 0; i < 4; ++i)
#pragma unroll
        for (int j = 0; j < 4; ++j) acc[i][j] = 0.f;
    const float* pwr[4];
#pragma unroll
    for (int j = 0; j < 4; ++j) pwr[j] = pw + (size_t)(d0 + tx * 4 + j) * 128;
    for (int k = 0; k < 128; k += 4) {
        float4 wv[4], av[4];
#pragma unroll
        for (int j = 0; j < 4; ++j) wv[j] = *reinterpret_cast<const float4*>(pwr[j] + k);
#pragma unroll
        for (int i = 0; i < 4; ++i) av[i] = *reinterpret_cast<const float4*>(&hbs[(ty * 4 + i) * 128 + k]);
#pragma unroll
        for (int i = 0; i < 4; ++i)
#pragma unroll
            for (int j = 0; j < 4; ++j)
                acc[i][j] += av[i].x * wv[j].x + av[i].y * wv[j].y +
                             av[i].z * wv[j].z + av[i].w * wv[j].w;
    }
#pragma unroll
    for (int i = 0; i < 4; ++i) {
        int bb = b0 + ty * 4 + i;
#pragma unroll
        for (int j = 0; j < 4; ++j) {
            int d = d0 + tx * 4 + j;
            h[(size_t)bb * DD + d] = acc[i][j] + pb[d];
        }
    }
}

// ------ router: logits, softmax, top-2 -> combine[b][8], top[b]=int2 ---------
__launch_bounds__(256)
__global__ void k_router(const float* __restrict__ h, const float* __restrict__ rw,
                         const float* __restrict__ rb, float* __restrict__ comb,
                         int2* __restrict__ top)
{
    const int lane = threadIdx.x & 63;
    const int b = blockIdx.x * 4 + (threadIdx.x >> 6);
    float part[6] = {0.f, 0.f, 0.f, 0.f, 0.f, 0.f};
    for (int j = 0; j < 16; ++j) {
        int d = j * 64 + lane;
        float hv = h[(size_t)b * DD + d];
#pragma unroll
        for (int e = 0; e < 6; ++e) part[e] += rw[e * DD + d] * hv;
    }
#pragma unroll
    for (int e = 0; e < 6; ++e) {
        float v = part[e];
        for (int off = 32; off > 0; off >>= 1) v += __shfl_xor(v, off);
        part[e] = v;
    }
    if (lane == 0) {
        float lgt[6];
#pragma unroll
        for (int e = 0; e < 6; ++e) lgt[e] = part[e] + rb[e];
        int i1 = 0;
#pragma unroll
        for (int e = 1; e < 6; ++e) if (lgt[e] > lgt[i1]) i1 = e;
        int i2 = -1;
#pragma unroll
        for (int e = 0; e < 6; ++e)
            if (e != i1 && (i2 < 0 || lgt[e] > lgt[i2])) i2 = e;
        float mx = lgt[i1], s = 0.f, ex[6];
#pragma unroll
        for (int e = 0; e < 6; ++e) { ex[e] = expf(lgt[e] - mx); s += ex[e]; }
        float inv = 1.f / s;
#pragma unroll
        for (int e = 0; e < 6; ++e) comb[b * 8 + e] = 0.f;
        comb[b * 8 + 6] = 0.f; comb[b * 8 + 7] = 0.f;
        comb[b * 8 + i1] = ex[i1] * inv;
        comb[b * 8 + i2] = ex[i2] * inv;
        top[b] = make_int2(i1, i2);
    }
}

// ------ index build: deterministic per-expert compact token lists ------------
__global__ void k_index(const int2* __restrict__ top, int* __restrict__ meta,
                        int* __restrict__ idxg)
{
    __shared__ int wsum[4];
    const int tid = threadIdx.x, lane = tid & 63, wid = tid >> 6;
    int2 tk[8];
#pragma unroll
    for (int j = 0; j < 8; ++j) tk[j] = top[tid * 8 + j];
    int off_run = 0;
    for (int e = 0; e < 6; ++e) {
        int m[8], c = 0;
#pragma unroll
        for (int j = 0; j < 8; ++j) { m[j] = (tk[j].x == e || tk[j].y == e) ? 1 : 0; c += m[j]; }
        int v = c;
        for (int d = 1; d < 64; d <<= 1) { int u = __shfl_up(v, d); if (lane >= d) v += u; }
        if (lane == 63) wsum[wid] = v;
        __syncthreads();
        int wbase = 0;
#pragma unroll
        for (int w = 0; w < 4; ++w) if (w < wid) wbase += wsum[w];
        int total = wsum[0] + wsum[1] + wsum[2] + wsum[3];
        int p = off_run + wbase + (v - c);
#pragma unroll
        for (int j = 0; j < 8; ++j) if (m[j]) idxg[p++] = tid * 8 + j;
        if (tid == 0) { meta[e] = total; meta[8 + e] = off_run; }
        off_run += total;
        __syncthreads();
    }
    if (tid == 0) meta[14] = off_run;
}

// ---------------- sparse MoE GEMMs + classifier ------------------------------
__device__ inline f16x8 cvt8(const float4 a, const float4 b)
{
    f16x8 r;
    r[0] = (f16_t)a.x; r[1] = (f16_t)a.y; r[2] = (f16_t)a.z; r[3] = (f16_t)a.w;
    r[4] = (f16_t)b.x; r[5] = (f16_t)b.y; r[6] = (f16_t)b.z; r[7] = (f16_t)b.w;
    return r;
}

// EPI 1: A = gather(h) f32, B = ew1, out = relu -> hidg (f16, compact rows)
// EPI 2: A = hidg f16,      B = ew2, out = scatter w*(c+b) -> eog f16 slots
// EPI 3: A = eog slot-sum,  B = cls_w, out = final logits f32
template<int EPI, int NFRAG>
__launch_bounds__(256, 3)
__global__ void k_moe(const float* __restrict__ hsrc, const f16_t* __restrict__ hidg,
                      const f16_t* __restrict__ eog, const float* __restrict__ Bp,
                      const float* __restrict__ bias, f16_t* __restrict__ outH,
                      f16_t* __restrict__ eogW, float* __restrict__ outF,
                      const float* __restrict__ comb, const int2* __restrict__ top,
                      const int* __restrict__ meta, const int* __restrict__ idxg,
                      int N, int K, int NCLIP)
{
    constexpr int BN = NFRAG * 32;
    __shared__ f16_t As[128 * 72];
    __shared__ f16_t Bs[BN * 72];
    const int tid = threadIdx.x;
    const int e  = blockIdx.z;
    const int m0 = blockIdx.x * 128, n0 = blockIdx.y * BN;
    int cnt = 1 << 30, off = 0;
    if (EPI != 3) {
        cnt = meta[e]; off = meta[8 + e];
        if (m0 >= cnt) return;
    }
    const int lane = tid & 63, wid = tid >> 6;
    const int l15 = lane & 15, lg = lane >> 4;
    const int wm = wid >> 1, wn = wid & 1;

    f32x4 acc[4][NFRAG];
#pragma unroll
    for (int i = 0; i < 4; ++i)
#pragma unroll
        for (int j = 0; j < NFRAG; ++j)
#pragma unroll
            for (int r = 0; r < 4; ++r) acc[i][j][r] = 0.f;

    for (int k0 = 0; k0 < K; k0 += 64) {
        __syncthreads();
        // ---- A stage: 128 rows x 64 halves (2 threads/row)
        {
            const int row = tid >> 1, c0 = (tid & 1) * 32;
            f16x8* d = reinterpret_cast<f16x8*>(As + row * 72 + c0);
            if (EPI == 1) {
                int lr = m0 + row;
                int token = (lr < cnt) ? idxg[off + lr] : 0;
                const float4* s = reinterpret_cast<const float4*>(hsrc + (size_t)token * K + k0 + c0);
#pragma unroll
                for (int j = 0; j < 4; ++j) d[j] = cvt8(s[2 * j], s[2 * j + 1]);
            } else if (EPI == 2) {
                const uint4* s = reinterpret_cast<const uint4*>(hidg + (size_t)(off + m0 + row) * K + k0 + c0);
#pragma unroll
                for (int j = 0; j < 4; ++j) reinterpret_cast<uint4*>(d)[j] = s[j];
            } else {
                int r = m0 + row;
                const f16x8* s0 = reinterpret_cast<const f16x8*>(eog + ((size_t)r * 2) * K + k0 + c0);
                const f16x8* s1 = reinterpret_cast<const f16x8*>(eog + ((size_t)r * 2 + 1) * K + k0 + c0);
#pragma unroll
                for (int j = 0; j < 4; ++j) d[j] = s0[j] + s1[j];
            }
        }
        // ---- B stage: BN rows x 64 halves (f32 -> f16)
        {
            constexpr int PERTHR = BN * 64 / 256;
            constexpr int TPR = 64 / PERTHR;
            const int row = tid / TPR, c0 = (tid % TPR) * PERTHR;
            const bool ok = (n0 + row) < NCLIP;
            const float4* s = reinterpret_cast<const float4*>(
                Bp + (size_t)e * N * K + (size_t)(n0 + row) * K + k0 + c0);
            f16x8* d = reinterpret_cast<f16x8*>(Bs + row * 72 + c0);
#pragma unroll
            for (int j = 0; j < PERTHR / 8; ++j) {
                float4 a = ok ? s[2 * j]     : make_float4(0.f, 0.f, 0.f, 0.f);
                float4 b = ok ? s[2 * j + 1] : make_float4(0.f, 0.f, 0.f, 0.f);
                d[j] = cvt8(a, b);
            }
        }
        __syncthreads();
#pragma unroll
        for (int kk = 0; kk < 64; kk += 32) {
            f16x8 af[4], bq[NFRAG];
#pragma unroll
            for (int i = 0; i < 4; ++i)
                af[i] = *reinterpret_cast<const f16x8*>(As + (wm * 64 + i * 16 + l15) * 72 + kk + lg * 8);
#pragma unroll
            for (int j = 0; j < NFRAG; ++j)
                bq[j] = *reinterpret_cast<const f16x8*>(Bs + (wn * (BN / 2) + j * 16 + l15) * 72 + kk + lg * 8);
#pragma unroll
            for (int i = 0; i < 4; ++i)
#pragma unroll
                for (int j = 0; j < NFRAG; ++j)
                    acc[i][j] = __builtin_amdgcn_mfma_f32_16x16x32_f16(af[i], bq[j], acc[i][j], 0, 0, 0);
        }
    }
#pragma unroll
    for (int i = 0; i < 4; ++i) {
#pragma unroll
        for (int j = 0; j < NFRAG; ++j) {
#pragma unroll
            for (int r = 0; r < 4; ++r) {
                int lr  = m0 + wm * 64 + i * 16 + lg * 4 + r;
                int col = n0 + wn * (BN / 2) + j * 16 + l15;
                float c = acc[i][j][r];
                if (EPI == 1) {
                    if (lr < cnt)
                        outH[(size_t)(off + lr) * N + col] = (f16_t)fmaxf(c + bias[(size_t)e * N + col], 0.f);
                } else if (EPI == 2) {
                    if (lr < cnt) {
                        int token = idxg[off + lr];
                        int slot = (top[token].x == e) ? 0 : 1;
                        float w = comb[token * 8 + e];
                        eogW[((size_t)token * 2 + slot) * N + col] = (f16_t)(w * (c + bias[(size_t)e * N + col]));
                    }
                } else {
                    if (col < NCLIP)
                        outF[(size_t)lr * NCLIP + col] = c + bias[col];
                }
            }
        }
    }
}

// -----------------------------------------------------------------------------
extern "C" void kernel_launch(void* const* d_in, const int* in_sizes, int n_in,
                              void* d_out, int out_size, void* d_ws, size_t ws_size,
                              hipStream_t stream)
{
    const float* x   = (const float*)d_in[0];
    const float* w1  = (const float*)d_in[1];
    const float* b1  = (const float*)d_in[2];
    const float* w2  = (const float*)d_in[3];
    const float* b2  = (const float*)d_in[4];
    const float* pw  = (const float*)d_in[5];
    const float* pb  = (const float*)d_in[6];
    const float* rw  = (const float*)d_in[7];
    const float* rb  = (const float*)d_in[8];
    const float* ew1 = (const float*)d_in[9];
    const float* eb1 = (const float*)d_in[10];
    const float* ew2 = (const float*)d_in[11];
    const float* eb2 = (const float*)d_in[12];
    const float* cw  = (const float*)d_in[13];
    const float* cb  = (const float*)d_in[14];
    float* out = (float*)d_out;

    char* ws = (char*)d_ws;
    bf16_t* wsw  = (bf16_t*)(ws + 0);            //  320 KB
    float*  hbar = (float*)(ws + 327680);        //    1 MB
    float*  h    = (float*)(ws + 1376256);       //    8 MB (f32) — later reused as eog
    f16_t*  eog  = (f16_t*)(ws + 1376256);       //    8 MB f16 [token][slot][D] (aliases h)
    float*  comb = (float*)(ws + 9764864);       //   64 KB
    int2*   top  = (int2*)(ws + 9830400);        //   16 KB
    int*    meta = (int*)(ws + 9846784);         //   64 B
    int*    idxg = (int*)(ws + 9847040);         //   16 KB
    f16_t*  hidg = (f16_t*)(ws + 9863424);       // 16.5 MB (4224 x 2048 f16, 128-row slack)

    k_prep_w2<<<320, 256, 0, stream>>>(w2, wsw);
    k_conv<<<2048, 256, 0, stream>>>(x, w1, b1, wsw, b2, hbar);
    k_proj<<<dim3(32, 16), 256, 0, stream>>>(hbar, pw, pb, h);
    k_router<<<512, 256, 0, stream>>>(h, rw, rb, comb, top);
    k_index<<<1, 256, 0, stream>>>(top, meta, idxg);
    // expert FFN layer 1: gathered tokens x ew1 -> hidg (relu, f16)
    k_moe<1, 4><<<dim3(16, 16, 6), 256, 0, stream>>>(
        h, nullptr, nullptr, ew1, eb1, hidg, nullptr, nullptr,
        comb, top, meta, idxg, HH, DD, HH);
    // expert FFN layer 2: hidg x ew2 -> eog (weighted, per-token slots)
    k_moe<2, 4><<<dim3(16, 8, 6), 256, 0, stream>>>(
        nullptr, hidg, nullptr, ew2, eb2, nullptr, eog, nullptr,
        comb, top, meta, idxg, DD, HH, DD);
    // classifier: (eog slot0 + slot1) x cls_w -> out
    k_moe<3, 2><<<dim3(16, 16, 1), 256, 0, stream>>>(
        nullptr, nullptr, eog, cw, cb, nullptr, nullptr, out,
        comb, top, meta, idxg, DD, DD, NC);
}